// Round 9
// baseline (479.059 us; speedup 1.0000x reference)
//
#include <hip/hip_runtime.h>
#include <cstdint>
#include <cstddef>

// Problem constants
#define NE      8192
#define DIM     256
#define NPOS    8192        // 2*4*32*32
#define ZELEMS  2097152     // 2*256*4096
#define NSTRIDE 1048576     // per-batch elements of z
#define SPATIAL 4096

// Packed-operand geometry: rows of 576 halfs = [hi(256) | lo(256) | slot(64)]
// GEMM K-schedule (9 steps of 64): zh*wh (0-3), zl*wh (4-7), ones*norm (8).
// Dropped zh*wl term -> score error std ~2.2e-3 scaled; flag threshold 0.05
// is ~22 sigma; flagged positions (~50) get exact fp64 recheck.
#define KTOT    576
#define KSTEP   64
#define NSTEPS  9
#define ROWB    1152        // KTOT * 2 bytes
#define ES      8           // e-splits (1024 e each)
#define PBLK    256         // positions per block

typedef _Float16 half8 __attribute__((ext_vector_type(8)));
typedef _Float16 half4 __attribute__((ext_vector_type(4)));
typedef float    f32x4 __attribute__((ext_vector_type(4)));

__device__ __forceinline__ unsigned ordmap(float f) {
    unsigned u = __float_as_uint(f);
    return u ^ (unsigned)(((int)u >> 31) | 0x80000000);
}
__device__ __forceinline__ float unord(unsigned long long k) {
    unsigned v = (unsigned)(k >> 13);
    unsigned u = (v & 0x80000000u) ? (v ^ 0x80000000u) : ~v;
    return __uint_as_float(u);
}

// ---------------------------------------------------------------------------
// conv_fused: blocks 0..127 pack z -> Apk; blocks 128..2175 pack w -> Bpk
// (4 e-rows per block, one per wave). Block 0 also zeroes count/done.
// ---------------------------------------------------------------------------
__global__ void conv_fused(const float* __restrict__ z, const float* __restrict__ w,
                           _Float16* __restrict__ Apk, _Float16* __restrict__ Bpk,
                           int* __restrict__ count, int* __restrict__ done) {
    const int tid = threadIdx.x;
    if (blockIdx.x == 0 && tid == 0) { *count = 0; *done = 0; }

    if (blockIdx.x < 128) {
        // ---- z path: 64 positions per block ----
        __shared__ float zt[256 * 64];
        const int pbase = blockIdx.x * 64;
        const int n = pbase >> 12;
        const int sbase = pbase & (SPATIAL - 1);
        const float* zsrc = z + (size_t)n * NSTRIDE + sbase;
        for (int i = tid; i < 256 * 64; i += 256) {
            int d = i >> 6, p = i & 63;
            zt[i] = zsrc[(size_t)d * SPATIAL + p];
        }
        __syncthreads();
        const int p = tid & 63, seg = tid >> 6;
        _Float16* rowp = Apk + (size_t)(pbase + p) * KTOT;
        for (int j8 = 0; j8 < 8; ++j8) {
            half8 hv, lv;
            #pragma unroll
            for (int jj = 0; jj < 8; ++jj) {
                int d = seg * 64 + j8 * 8 + jj;
                float v = -2.0f * zt[d * 64 + p];
                _Float16 h = (_Float16)v;
                hv[jj] = h;
                lv[jj] = (_Float16)(v - (float)h);
            }
            *(half8*)(rowp + seg * 64 + j8 * 8) = hv;
            *(half8*)(rowp + 256 + seg * 64 + j8 * 8) = lv;
        }
        if (tid < 64) {
            _Float16* r2 = Apk + (size_t)(pbase + tid) * KTOT + 512;
            #pragma unroll
            for (int q = 0; q < 8; ++q) {
                half8 v8;
                #pragma unroll
                for (int jj = 0; jj < 8; ++jj) v8[jj] = (_Float16)0.0f;
                if (q == 0) { v8[0] = (_Float16)1.0f; v8[1] = (_Float16)1.0f; }
                *(half8*)(r2 + q * 8) = v8;
            }
        }
    } else {
        // ---- w path: one e-row per wave ----
        const int lane = tid & 63;
        const int e = (blockIdx.x - 128) * 4 + (tid >> 6);
        const float4 v = *(const float4*)(w + (size_t)e * DIM + lane * 4);
        half4 h, l;
        {
            float a0 = v.x * 8192.0f, a1 = v.y * 8192.0f,
                  a2 = v.z * 8192.0f, a3 = v.w * 8192.0f;
            h[0] = (_Float16)a0; l[0] = (_Float16)(a0 - (float)h[0]);
            h[1] = (_Float16)a1; l[1] = (_Float16)(a1 - (float)h[1]);
            h[2] = (_Float16)a2; l[2] = (_Float16)(a2 - (float)h[2]);
            h[3] = (_Float16)a3; l[3] = (_Float16)(a3 - (float)h[3]);
        }
        _Float16* row = Bpk + (size_t)e * KTOT;
        *(half4*)(row + lane * 4) = h;
        *(half4*)(row + 256 + lane * 4) = l;
        float sq = v.x * v.x + v.y * v.y + v.z * v.z + v.w * v.w;
        #pragma unroll
        for (int off = 32; off; off >>= 1) sq += __shfl_down(sq, off);
        float nrm = __shfl(sq, 0) * 8192.0f;
        _Float16 nh = (_Float16)nrm;
        _Float16 nl = (_Float16)(nrm - (float)nh);
        row[512 + lane] = (lane == 0) ? nh : (lane == 1) ? nl : (_Float16)0.0f;
    }
}

// ---------------------------------------------------------------------------
// vq_gemm: scaled score C[e][pos] with fused per-position argmin (+2nd best).
// 256 blocks = 32 pos-tiles x 8 e-splits; 8 waves; wave tile 128e x 64pos;
// K-step 64 double-buffered; T2 16B-chunk XOR swizzle via pre-swizzled source.
// 8-phase-style schedule (T3+T4+T5): each K-step = 4 phases of
// {ds-read subtile + partial STAGE issue; s_barrier; setprio(1); 16 MFMA;
//  setprio(0); s_barrier}, full vmcnt drain only at K-step tail (2 buffers).
// ---------------------------------------------------------------------------
__global__ __launch_bounds__(512, 2) void vq_gemm(
        const _Float16* __restrict__ Apk, const _Float16* __restrict__ Bpk,
        unsigned long long* __restrict__ parts) {
    __shared__ _Float16 Asl[2][PBLK * KSTEP];
    __shared__ _Float16 Bsl[2][256 * KSTEP];

    const int tid = threadIdx.x;
    const int lane = tid & 63;
    const int wid = tid >> 6;
    const int wm = wid >> 2, wn = wid & 3;
    const int es = blockIdx.x & 7, pt = blockIdx.x >> 3;
    const int l15 = lane & 15, l4 = lane >> 4, l7 = lane & 7;
    const int co0 = (l4 ^ l7) << 4;
    const int co1 = ((4 + l4) ^ l7) << 4;
    const int aoff = (wm * 128 + l15) * 128;   // into Bsl (e rows)
    const int boff = (wn * 64 + l15) * 128;    // into Asl (pos rows)

    const int srow = tid >> 3;
    const int schunk = tid & 7;
    const int sw = ((schunk ^ (srow & 7)) << 4);

    const char* Ag = (const char*)(Apk + (size_t)pt * PBLK * KTOT);
    const char* Bg0 = (const char*)(Bpk + (size_t)es * 1024 * KTOT);

    // per-step source 64-half slot within each row:
    // steps 0-3: zh*wh, 4-7: zl*wh, 8: ones*norm
    const int AKT[NSTEPS] = {0,1,2,3, 4,5,6,7, 8};
    const int BKT[NSTEPS] = {0,1,2,3, 0,1,2,3, 8};

#define STAGE_R(gbase, lbase, ktv, IBEG, IEND) {                            \
        _Pragma("unroll")                                                   \
        for (int i_ = (IBEG); i_ < (IEND); ++i_) {                          \
            int r_ = srow + i_ * 64;                                        \
            const char* g_ = (gbase) + (size_t)r_ * ROWB + (ktv) * 128 + sw;\
            char* lp_ = (char*)(lbase) + r_ * 128 + schunk * 16;            \
            __builtin_amdgcn_global_load_lds(                               \
                (const __attribute__((address_space(1))) void*)g_,          \
                (__attribute__((address_space(3))) void*)lp_, 16, 0, 0);    \
        } }

    float b1[4], b2[4]; int e1[4];
    #pragma unroll
    for (int q = 0; q < 4; ++q) { b1[q] = 3.0e38f; b2[q] = 3.0e38f; e1[q] = 0; }

    for (int st = 0; st < 4; ++st) {
        const char* Bg = Bg0 + (size_t)st * 256 * ROWB;
        STAGE_R(Ag, Asl[0], AKT[0], 0, 4);
        STAGE_R(Bg, Bsl[0], BKT[0], 0, 4);
        __syncthreads();   // full drain: buffer 0 ready

        f32x4 acc[8][4];
        #pragma unroll
        for (int mi = 0; mi < 8; ++mi)
            #pragma unroll
            for (int ni = 0; ni < 4; ++ni) acc[mi][ni] = (f32x4)0.0f;

        #pragma unroll
        for (int kt = 0; kt < NSTEPS; ++kt) {
            const int cb = kt & 1;
            const char* Ab = (const char*)Asl[cb];
            const char* Bb = (const char*)Bsl[cb];
            const bool hn = (kt < NSTEPS - 1);
            half8 af0[8], af1[8], bfp[2];

            // ---- phase 1: af0 + bf[0..1] (kb0); issue next A stage
            #pragma unroll
            for (int mi = 0; mi < 8; ++mi)
                af0[mi] = *(const half8*)(Bb + aoff + mi * 2048 + co0);
            bfp[0] = *(const half8*)(Ab + boff + 0 * 2048 + co0);
            bfp[1] = *(const half8*)(Ab + boff + 1 * 2048 + co0);
            if (hn) STAGE_R(Ag, Asl[cb ^ 1], AKT[kt + 1], 0, 4);
            __builtin_amdgcn_s_barrier();
            __builtin_amdgcn_s_setprio(1);
            #pragma unroll
            for (int mi = 0; mi < 8; ++mi) {
                acc[mi][0] = __builtin_amdgcn_mfma_f32_16x16x32_f16(af0[mi], bfp[0], acc[mi][0], 0, 0, 0);
                acc[mi][1] = __builtin_amdgcn_mfma_f32_16x16x32_f16(af0[mi], bfp[1], acc[mi][1], 0, 0, 0);
            }
            __builtin_amdgcn_s_setprio(0);
            __builtin_amdgcn_s_barrier();

            // ---- phase 2: bf[2..3] (kb0); issue next B stage (half 1)
            bfp[0] = *(const half8*)(Ab + boff + 2 * 2048 + co0);
            bfp[1] = *(const half8*)(Ab + boff + 3 * 2048 + co0);
            if (hn) STAGE_R(Bg, Bsl[cb ^ 1], BKT[kt + 1], 0, 2);
            __builtin_amdgcn_s_barrier();
            __builtin_amdgcn_s_setprio(1);
            #pragma unroll
            for (int mi = 0; mi < 8; ++mi) {
                acc[mi][2] = __builtin_amdgcn_mfma_f32_16x16x32_f16(af0[mi], bfp[0], acc[mi][2], 0, 0, 0);
                acc[mi][3] = __builtin_amdgcn_mfma_f32_16x16x32_f16(af0[mi], bfp[1], acc[mi][3], 0, 0, 0);
            }
            __builtin_amdgcn_s_setprio(0);
            __builtin_amdgcn_s_barrier();

            // ---- phase 3: af1 + bf[0..1] (kb1); issue next B stage (half 2)
            #pragma unroll
            for (int mi = 0; mi < 8; ++mi)
                af1[mi] = *(const half8*)(Bb + aoff + mi * 2048 + co1);
            bfp[0] = *(const half8*)(Ab + boff + 0 * 2048 + co1);
            bfp[1] = *(const half8*)(Ab + boff + 1 * 2048 + co1);
            if (hn) STAGE_R(Bg, Bsl[cb ^ 1], BKT[kt + 1], 2, 4);
            __builtin_amdgcn_s_barrier();
            __builtin_amdgcn_s_setprio(1);
            #pragma unroll
            for (int mi = 0; mi < 8; ++mi) {
                acc[mi][0] = __builtin_amdgcn_mfma_f32_16x16x32_f16(af1[mi], bfp[0], acc[mi][0], 0, 0, 0);
                acc[mi][1] = __builtin_amdgcn_mfma_f32_16x16x32_f16(af1[mi], bfp[1], acc[mi][1], 0, 0, 0);
            }
            __builtin_amdgcn_s_setprio(0);
            __builtin_amdgcn_s_barrier();

            // ---- phase 4: bf[2..3] (kb1); MFMA; then full drain for dbuf swap
            bfp[0] = *(const half8*)(Ab + boff + 2 * 2048 + co1);
            bfp[1] = *(const half8*)(Ab + boff + 3 * 2048 + co1);
            __builtin_amdgcn_s_barrier();
            __builtin_amdgcn_s_setprio(1);
            #pragma unroll
            for (int mi = 0; mi < 8; ++mi) {
                acc[mi][2] = __builtin_amdgcn_mfma_f32_16x16x32_f16(af1[mi], bfp[0], acc[mi][2], 0, 0, 0);
                acc[mi][3] = __builtin_amdgcn_mfma_f32_16x16x32_f16(af1[mi], bfp[1], acc[mi][3], 0, 0, 0);
            }
            __builtin_amdgcn_s_setprio(0);
            __syncthreads();   // vmcnt(0)+lgkmcnt(0): next buffer ready
        }

        const int ebl = es * 1024 + st * 256 + wm * 128 + (l4 << 2);
        #pragma unroll
        for (int mi = 0; mi < 8; ++mi)
            #pragma unroll
            for (int ni = 0; ni < 4; ++ni)
                #pragma unroll
                for (int r = 0; r < 4; ++r) {
                    float v = acc[mi][ni][r];
                    int e = ebl + mi * 16 + r;
                    bool c = v < b1[ni];
                    b2[ni] = fminf(b2[ni], fmaxf(v, b1[ni]));
                    b1[ni] = c ? v : b1[ni];
                    e1[ni] = c ? e : e1[ni];
                }
    }

    #pragma unroll
    for (int ni = 0; ni < 4; ++ni) {
        unsigned long long k1 =
            (((unsigned long long)ordmap(b1[ni])) << 13) | (unsigned)e1[ni];
        unsigned long long k2 = ((unsigned long long)ordmap(b2[ni])) << 13;
        #pragma unroll
        for (int m = 16; m <= 32; m <<= 1) {
            unsigned long long o1 = __shfl_xor(k1, m, 64);
            unsigned long long o2 = __shfl_xor(k2, m, 64);
            unsigned long long mx = k1 > o1 ? k1 : o1;
            k1 = k1 < o1 ? k1 : o1;
            k2 = k2 < o2 ? k2 : o2;
            k2 = k2 < mx ? k2 : mx;
        }
        if (lane < 16) {
            int pos = pt * PBLK + wn * 64 + ni * 16 + l15;
            unsigned long long* pp = parts + (((size_t)(wm * 8 + es)) * NPOS + pos) * 2;
            pp[0] = k1; pp[1] = k2;
        }
    }
#undef STAGE_R
}

// ---------------------------------------------------------------------------
// combine: merge 16 (best, 2nd) pairs; flag gaps < 0.05 scaled (~22 sigma of
// the 2.2e-3 dropped-term error) and RESET their key so vq_exact owns it.
// ---------------------------------------------------------------------------
__global__ void vq_combine(const unsigned long long* __restrict__ parts,
                           unsigned long long* __restrict__ keys,
                           int* __restrict__ count, int* __restrict__ list) {
    int pos = blockIdx.x * 256 + threadIdx.x;
    unsigned long long g1 = ~0ull, g2 = ~0ull;
    for (int s = 0; s < 16; ++s) {
        const unsigned long long* pp = parts + (((size_t)s) * NPOS + pos) * 2;
        unsigned long long a1 = pp[0], a2 = pp[1];
        unsigned long long mx = g1 > a1 ? g1 : a1;
        g1 = g1 < a1 ? g1 : a1;
        g2 = g2 < a2 ? g2 : a2;
        g2 = g2 < mx ? g2 : mx;
    }
    if (unord(g2) - unord(g1) < 0.05f) {
        int ix = atomicAdd(count, 1);
        list[ix] = pos;            // list capacity = NPOS, cannot overflow
        keys[pos] = ~0ull;         // exact recheck fully determines this pos
    } else {
        keys[pos] = g1;
    }
}

// ---------------------------------------------------------------------------
// exact recheck (fp64), chunked: work-item = (flagged pos, 256-e chunk).
// 1024-block grid-stride; block-reduce then atomicMin into keys[pos].
// ---------------------------------------------------------------------------
#define NCHUNK 32
__global__ void vq_exact(const float* __restrict__ z, const float* __restrict__ w,
                         const int* __restrict__ list, const int* __restrict__ count,
                         unsigned long long* __restrict__ keys) {
    __shared__ float zv[256];
    __shared__ unsigned long long wk[4];
    const int t = threadIdx.x;
    int cnt = *count; if (cnt > NPOS) cnt = NPOS;
    int nwork = cnt * NCHUNK;
    for (int item = blockIdx.x; item < nwork; item += gridDim.x) {
        int pos = list[item >> 5];
        int c = item & (NCHUNK - 1);
        int n = pos >> 12, s = pos & (SPATIAL - 1);
        zv[t] = z[(size_t)n * NSTRIDE + (size_t)t * SPATIAL + s];
        __syncthreads();

        int e = c * 256 + t;                 // one embedding per thread
        const float* wr = w + (size_t)e * DIM;
        double nrm = 0.0, dt = 0.0;
        #pragma unroll 4
        for (int d = 0; d < DIM; d += 4) {
            float4 w4 = *(const float4*)(wr + d);
            nrm += (double)w4.x * w4.x + (double)w4.y * w4.y
                 + (double)w4.z * w4.z + (double)w4.w * w4.w;
            dt  += (double)w4.x * zv[d] + (double)w4.y * zv[d + 1]
                 + (double)w4.z * zv[d + 2] + (double)w4.w * zv[d + 3];
        }
        // match GEMM scaling (x8192) so keys are comparable across paths
        float sc = (float)(8192.0 * (nrm - 2.0 * dt));
        unsigned long long k = (((unsigned long long)ordmap(sc)) << 13) | (unsigned)e;
        #pragma unroll
        for (int off = 32; off; off >>= 1) {
            unsigned long long o = __shfl_down(k, off, 64);
            k = k < o ? k : o;
        }
        if ((t & 63) == 0) wk[t >> 6] = k;
        __syncthreads();
        if (t == 0) {
            unsigned long long m0 = wk[0] < wk[1] ? wk[0] : wk[1];
            unsigned long long m1 = wk[2] < wk[3] ? wk[2] : wk[3];
            unsigned long long m = m0 < m1 ? m0 : m1;
            atomicMin(&keys[pos], m);
        }
        __syncthreads();
    }
}

// ---------------------------------------------------------------------------
// vq_out: gather z_q, straight-through output, loss partials, index map;
// last block (done-counter) reduces partials and writes the loss scalar.
// ---------------------------------------------------------------------------
__global__ void vq_out(const float* __restrict__ z, const float* __restrict__ w,
                       const unsigned long long* __restrict__ keys,
                       float* __restrict__ out, float* __restrict__ partial,
                       int* __restrict__ done) {
    __shared__ float red[4];
    __shared__ int isLast;
    const int tid = threadIdx.x;
    int gi = blockIdx.x * 256 + tid;
    int n = gi >> 20;
    int r = gi & (NSTRIDE - 1);
    int d = r >> 12;
    int s = r & (SPATIAL - 1);
    int p = (n << 12) | s;

    int e = (int)(keys[p] & 8191ull);
    float zl = z[gi];
    float zq = w[(size_t)e * DIM + d];
    out[gi] = zl + (zq - zl);

    float diff = zq - zl;
    float ls = diff * diff;
    #pragma unroll
    for (int off = 32; off; off >>= 1) ls += __shfl_down(ls, off);
    if ((tid & 63) == 0) red[tid >> 6] = ls;

    if (gi < NPOS) {
        int ei = (int)(keys[gi] & 8191ull);
        out[ZELEMS + 1 + gi] = (float)ei;
    }
    __syncthreads();
    if (tid == 0) {
        partial[blockIdx.x] = red[0] + red[1] + red[2] + red[3];
        __threadfence();
        isLast = (atomicAdd(done, 1) == (int)gridDim.x - 1);
    }
    __syncthreads();
    if (isLast) {
        __threadfence();
        float sum = 0.f;
        for (int i = tid; i < 8192; i += 256) sum += partial[i];
        #pragma unroll
        for (int off = 32; off; off >>= 1) sum += __shfl_down(sum, off);
        if ((tid & 63) == 0) red[tid >> 6] = sum;
        __syncthreads();
        if (tid == 0)
            out[ZELEMS] = 1.25f * (red[0] + red[1] + red[2] + red[3]) / (float)ZELEMS;
    }
}

// ---------------------------------------------------------------------------
extern "C" void kernel_launch(void* const* d_in, const int* in_sizes, int n_in,
                              void* d_out, int out_size, void* d_ws, size_t ws_size,
                              hipStream_t stream) {
    const float* z = (const float*)d_in[0];
    const float* w = (const float*)d_in[1];
    float* out = (float*)d_out;

    char* wsb = (char*)d_ws;
    _Float16* Apk = (_Float16*)(wsb);                                  //  9,437,184
    _Float16* Bpk = (_Float16*)(wsb + 9437184);                        //  9,437,184
    unsigned long long* parts = (unsigned long long*)(wsb + 18874368); //  2,097,152
    unsigned long long* keys  = (unsigned long long*)(wsb + 20971520); //     65,536
    int*   count   = (int*)(wsb + 21037056);                           //          4
    int*   done    = (int*)(wsb + 21037060);                           //          4
    int*   list    = (int*)(wsb + 21037072);                           //     32,768
    float* partial = (float*)(wsb + 21069856);                         //     32,768

    conv_fused<<<128 + NE / 4, 256, 0, stream>>>(z, w, Apk, Bpk, count, done);
    vq_gemm<<<(NPOS / PBLK) * ES, 512, 0, stream>>>(Apk, Bpk, parts);
    vq_combine<<<NPOS / 256, 256, 0, stream>>>(parts, keys, count, list);
    vq_exact<<<1024, 256, 0, stream>>>(z, w, list, count, keys);
    vq_out<<<ZELEMS / 256, 256, 0, stream>>>(z, w, keys, out, partial, done);
}

// Round 12
// 296.496 us; speedup vs baseline: 1.6157x; 1.6157x over previous
//
#include <hip/hip_runtime.h>
#include <cstdint>
#include <cstddef>

// Problem constants
#define NE      8192
#define DIM     256
#define NPOS    8192        // 2*4*32*32
#define ZELEMS  2097152     // 2*256*4096
#define NSTRIDE 1048576     // per-batch elements of z
#define SPATIAL 4096

// Packed-operand geometry: rows of 576 halfs = [hi(256) | lo(256) | slot(64)]
// GEMM K-schedule (9 steps of 64): zh*wh (0-3), zl*wh (4-7), ones*norm (8).
// Dropped zh*wl term -> score error std ~2.2e-3 scaled; flag threshold 0.05
// is ~22 sigma; flagged positions (~50) get exact fp64 recheck.
#define KTOT    576
#define KSTEP   64
#define NSTEPS  9
#define ROWB    1152        // KTOT * 2 bytes
#define ES      8           // e-splits (1024 e each)
#define PBLK    256         // positions per block
#define NOUTBLK 2048        // vq_out blocks (4 elems/thread)

typedef _Float16 half8 __attribute__((ext_vector_type(8)));
typedef _Float16 half4 __attribute__((ext_vector_type(4)));
typedef float    f32x4 __attribute__((ext_vector_type(4)));

__device__ __forceinline__ unsigned ordmap(float f) {
    unsigned u = __float_as_uint(f);
    return u ^ (unsigned)(((int)u >> 31) | 0x80000000);
}
__device__ __forceinline__ float unord(unsigned long long k) {
    unsigned v = (unsigned)(k >> 13);
    unsigned u = (v & 0x80000000u) ? (v ^ 0x80000000u) : ~v;
    return __uint_as_float(u);
}

// ---------------------------------------------------------------------------
// conv_fused: blocks 0..127 pack z -> Apk; blocks 128..2175 pack w -> Bpk
// (4 e-rows per block, one per wave). Block 0 also zeroes count.
// ---------------------------------------------------------------------------
__global__ void conv_fused(const float* __restrict__ z, const float* __restrict__ w,
                           _Float16* __restrict__ Apk, _Float16* __restrict__ Bpk,
                           int* __restrict__ count) {
    const int tid = threadIdx.x;
    if (blockIdx.x == 0 && tid == 0) { *count = 0; }

    if (blockIdx.x < 128) {
        // ---- z path: 64 positions per block ----
        __shared__ float zt[256 * 64];
        const int pbase = blockIdx.x * 64;
        const int n = pbase >> 12;
        const int sbase = pbase & (SPATIAL - 1);
        const float* zsrc = z + (size_t)n * NSTRIDE + sbase;
        for (int i = tid; i < 256 * 64; i += 256) {
            int d = i >> 6, p = i & 63;
            zt[i] = zsrc[(size_t)d * SPATIAL + p];
        }
        __syncthreads();
        const int p = tid & 63, seg = tid >> 6;
        _Float16* rowp = Apk + (size_t)(pbase + p) * KTOT;
        for (int j8 = 0; j8 < 8; ++j8) {
            half8 hv, lv;
            #pragma unroll
            for (int jj = 0; jj < 8; ++jj) {
                int d = seg * 64 + j8 * 8 + jj;
                float v = -2.0f * zt[d * 64 + p];
                _Float16 h = (_Float16)v;
                hv[jj] = h;
                lv[jj] = (_Float16)(v - (float)h);
            }
            *(half8*)(rowp + seg * 64 + j8 * 8) = hv;
            *(half8*)(rowp + 256 + seg * 64 + j8 * 8) = lv;
        }
        if (tid < 64) {
            _Float16* r2 = Apk + (size_t)(pbase + tid) * KTOT + 512;
            #pragma unroll
            for (int q = 0; q < 8; ++q) {
                half8 v8;
                #pragma unroll
                for (int jj = 0; jj < 8; ++jj) v8[jj] = (_Float16)0.0f;
                if (q == 0) { v8[0] = (_Float16)1.0f; v8[1] = (_Float16)1.0f; }
                *(half8*)(r2 + q * 8) = v8;
            }
        }
    } else {
        // ---- w path: one e-row per wave ----
        const int lane = tid & 63;
        const int e = (blockIdx.x - 128) * 4 + (tid >> 6);
        const float4 v = *(const float4*)(w + (size_t)e * DIM + lane * 4);
        half4 h, l;
        {
            float a0 = v.x * 8192.0f, a1 = v.y * 8192.0f,
                  a2 = v.z * 8192.0f, a3 = v.w * 8192.0f;
            h[0] = (_Float16)a0; l[0] = (_Float16)(a0 - (float)h[0]);
            h[1] = (_Float16)a1; l[1] = (_Float16)(a1 - (float)h[1]);
            h[2] = (_Float16)a2; l[2] = (_Float16)(a2 - (float)h[2]);
            h[3] = (_Float16)a3; l[3] = (_Float16)(a3 - (float)h[3]);
        }
        _Float16* row = Bpk + (size_t)e * KTOT;
        *(half4*)(row + lane * 4) = h;
        *(half4*)(row + 256 + lane * 4) = l;
        float sq = v.x * v.x + v.y * v.y + v.z * v.z + v.w * v.w;
        #pragma unroll
        for (int off = 32; off; off >>= 1) sq += __shfl_down(sq, off);
        float nrm = __shfl(sq, 0) * 8192.0f;
        _Float16 nh = (_Float16)nrm;
        _Float16 nl = (_Float16)(nrm - (float)nh);
        row[512 + lane] = (lane == 0) ? nh : (lane == 1) ? nl : (_Float16)0.0f;
    }
}

// ---------------------------------------------------------------------------
// vq_gemm: scaled score C[e][pos] with fused per-position argmin (+2nd best).
// EXACT round-7 structure (measured 134 us): 2-phase minimum schedule, one
// vmcnt(0)+barrier per K-step; T2 16B-chunk XOR swizzle via pre-swizzled src.
// ---------------------------------------------------------------------------
__global__ __launch_bounds__(512, 2) void vq_gemm(
        const _Float16* __restrict__ Apk, const _Float16* __restrict__ Bpk,
        unsigned long long* __restrict__ parts) {
    __shared__ _Float16 Asl[2][PBLK * KSTEP];
    __shared__ _Float16 Bsl[2][256 * KSTEP];

    const int tid = threadIdx.x;
    const int lane = tid & 63;
    const int wid = tid >> 6;
    const int wm = wid >> 2, wn = wid & 3;
    const int es = blockIdx.x & 7, pt = blockIdx.x >> 3;
    const int l15 = lane & 15, l4 = lane >> 4, l7 = lane & 7;
    const int co0 = (l4 ^ l7) << 4;
    const int co1 = ((4 + l4) ^ l7) << 4;
    const int aoff = (wm * 128 + l15) * 128;   // into Bsl (e rows)
    const int boff = (wn * 64 + l15) * 128;    // into Asl (pos rows)

    const int srow = tid >> 3;
    const int schunk = tid & 7;
    const int sw = ((schunk ^ (srow & 7)) << 4);

    const char* Ag = (const char*)(Apk + (size_t)pt * PBLK * KTOT);
    const char* Bg0 = (const char*)(Bpk + (size_t)es * 1024 * KTOT);

    // per-step source 64-half slot within each row:
    // steps 0-3: zh*wh, 4-7: zl*wh, 8: ones*norm
    const int AKT[NSTEPS] = {0,1,2,3, 4,5,6,7, 8};
    const int BKT[NSTEPS] = {0,1,2,3, 0,1,2,3, 8};

#define STAGE(gbase, lbase, ktv) {                                          \
        _Pragma("unroll")                                                   \
        for (int i_ = 0; i_ < 4; ++i_) {                                    \
            int r_ = srow + i_ * 64;                                        \
            const char* g_ = (gbase) + (size_t)r_ * ROWB + (ktv) * 128 + sw;\
            char* lp_ = (char*)(lbase) + r_ * 128 + schunk * 16;            \
            __builtin_amdgcn_global_load_lds(                               \
                (const __attribute__((address_space(1))) void*)g_,          \
                (__attribute__((address_space(3))) void*)lp_, 16, 0, 0);    \
        } }

    float b1[4], b2[4]; int e1[4];
    #pragma unroll
    for (int q = 0; q < 4; ++q) { b1[q] = 3.0e38f; b2[q] = 3.0e38f; e1[q] = 0; }

    for (int st = 0; st < 4; ++st) {
        const char* Bg = Bg0 + (size_t)st * 256 * ROWB;
        STAGE(Ag, Asl[0], 0);
        STAGE(Bg, Bsl[0], 0);
        __syncthreads();

        f32x4 acc[8][4];
        #pragma unroll
        for (int mi = 0; mi < 8; ++mi)
            #pragma unroll
            for (int ni = 0; ni < 4; ++ni) acc[mi][ni] = (f32x4)0.0f;

        #pragma unroll
        for (int kt = 0; kt < NSTEPS; ++kt) {
            const int cb = kt & 1;
            if (kt < NSTEPS - 1) {
                STAGE(Ag, Asl[cb ^ 1], AKT[kt + 1]);
                STAGE(Bg, Bsl[cb ^ 1], BKT[kt + 1]);
            }
            const char* Ab = (const char*)Asl[cb];
            const char* Bb = (const char*)Bsl[cb];
            #pragma unroll
            for (int kb = 0; kb < 2; ++kb) {
                const int co = kb ? co1 : co0;
                half8 af[8], bf[4];
                #pragma unroll
                for (int mi = 0; mi < 8; ++mi)
                    af[mi] = *(const half8*)(Bb + aoff + mi * 2048 + co);
                #pragma unroll
                for (int ni = 0; ni < 4; ++ni)
                    bf[ni] = *(const half8*)(Ab + boff + ni * 2048 + co);
                #pragma unroll
                for (int mi = 0; mi < 8; ++mi)
                    #pragma unroll
                    for (int ni = 0; ni < 4; ++ni)
                        acc[mi][ni] = __builtin_amdgcn_mfma_f32_16x16x32_f16(
                            af[mi], bf[ni], acc[mi][ni], 0, 0, 0);
            }
            __syncthreads();
        }

        const int ebl = es * 1024 + st * 256 + wm * 128 + (l4 << 2);
        #pragma unroll
        for (int mi = 0; mi < 8; ++mi)
            #pragma unroll
            for (int ni = 0; ni < 4; ++ni)
                #pragma unroll
                for (int r = 0; r < 4; ++r) {
                    float v = acc[mi][ni][r];
                    int e = ebl + mi * 16 + r;
                    bool c = v < b1[ni];
                    b2[ni] = fminf(b2[ni], fmaxf(v, b1[ni]));
                    b1[ni] = c ? v : b1[ni];
                    e1[ni] = c ? e : e1[ni];
                }
    }

    #pragma unroll
    for (int ni = 0; ni < 4; ++ni) {
        unsigned long long k1 =
            (((unsigned long long)ordmap(b1[ni])) << 13) | (unsigned)e1[ni];
        unsigned long long k2 = ((unsigned long long)ordmap(b2[ni])) << 13;
        #pragma unroll
        for (int m = 16; m <= 32; m <<= 1) {
            unsigned long long o1 = __shfl_xor(k1, m, 64);
            unsigned long long o2 = __shfl_xor(k2, m, 64);
            unsigned long long mx = k1 > o1 ? k1 : o1;
            k1 = k1 < o1 ? k1 : o1;
            k2 = k2 < o2 ? k2 : o2;
            k2 = k2 < mx ? k2 : mx;
        }
        if (lane < 16) {
            int pos = pt * PBLK + wn * 64 + ni * 16 + l15;
            unsigned long long* pp = parts + (((size_t)(wm * 8 + es)) * NPOS + pos) * 2;
            pp[0] = k1; pp[1] = k2;
        }
    }
#undef STAGE
}

// ---------------------------------------------------------------------------
// combine: merge 16 (best, 2nd) pairs; flag gaps < 0.05 scaled (~22 sigma of
// the 2.2e-3 dropped-term error) and RESET their key so vq_exact owns it.
// ---------------------------------------------------------------------------
__global__ void vq_combine(const unsigned long long* __restrict__ parts,
                           unsigned long long* __restrict__ keys,
                           int* __restrict__ count, int* __restrict__ list) {
    int pos = blockIdx.x * 256 + threadIdx.x;
    unsigned long long g1 = ~0ull, g2 = ~0ull;
    for (int s = 0; s < 16; ++s) {
        const unsigned long long* pp = parts + (((size_t)s) * NPOS + pos) * 2;
        unsigned long long a1 = pp[0], a2 = pp[1];
        unsigned long long mx = g1 > a1 ? g1 : a1;
        g1 = g1 < a1 ? g1 : a1;
        g2 = g2 < a2 ? g2 : a2;
        g2 = g2 < mx ? g2 : mx;
    }
    if (unord(g2) - unord(g1) < 0.05f) {
        int ix = atomicAdd(count, 1);
        list[ix] = pos;            // list capacity = NPOS, cannot overflow
        keys[pos] = ~0ull;         // exact recheck fully determines this pos
    } else {
        keys[pos] = g1;
    }
}

// ---------------------------------------------------------------------------
// exact recheck (fp64), chunked: work-item = (flagged pos, 256-e chunk).
// 1024-block grid-stride; block-reduce then atomicMin into keys[pos].
// ---------------------------------------------------------------------------
#define NCHUNK 32
__global__ void vq_exact(const float* __restrict__ z, const float* __restrict__ w,
                         const int* __restrict__ list, const int* __restrict__ count,
                         unsigned long long* __restrict__ keys) {
    __shared__ float zv[256];
    __shared__ unsigned long long wk[4];
    const int t = threadIdx.x;
    int cnt = *count; if (cnt > NPOS) cnt = NPOS;
    int nwork = cnt * NCHUNK;
    for (int item = blockIdx.x; item < nwork; item += gridDim.x) {
        int pos = list[item >> 5];
        int c = item & (NCHUNK - 1);
        int n = pos >> 12, s = pos & (SPATIAL - 1);
        zv[t] = z[(size_t)n * NSTRIDE + (size_t)t * SPATIAL + s];
        __syncthreads();

        int e = c * 256 + t;                 // one embedding per thread
        const float* wr = w + (size_t)e * DIM;
        double nrm = 0.0, dt = 0.0;
        #pragma unroll 4
        for (int d = 0; d < DIM; d += 4) {
            float4 w4 = *(const float4*)(wr + d);
            nrm += (double)w4.x * w4.x + (double)w4.y * w4.y
                 + (double)w4.z * w4.z + (double)w4.w * w4.w;
            dt  += (double)w4.x * zv[d] + (double)w4.y * zv[d + 1]
                 + (double)w4.z * zv[d + 2] + (double)w4.w * zv[d + 3];
        }
        // match GEMM scaling (x8192) so keys are comparable across paths
        float sc = (float)(8192.0 * (nrm - 2.0 * dt));
        unsigned long long k = (((unsigned long long)ordmap(sc)) << 13) | (unsigned)e;
        #pragma unroll
        for (int off = 32; off; off >>= 1) {
            unsigned long long o = __shfl_down(k, off, 64);
            k = k < o ? k : o;
        }
        if ((t & 63) == 0) wk[t >> 6] = k;
        __syncthreads();
        if (t == 0) {
            unsigned long long m0 = wk[0] < wk[1] ? wk[0] : wk[1];
            unsigned long long m1 = wk[2] < wk[3] ? wk[2] : wk[3];
            unsigned long long m = m0 < m1 ? m0 : m1;
            atomicMin(&keys[pos], m);
        }
        __syncthreads();
    }
}

// ---------------------------------------------------------------------------
// vq_out: 4 consecutive positions per thread (float4 z/out, 4 independent
// w-gathers in flight), loss partials per block, float4 index write.
// No fences, no global atomics (round-9 regression reverted).
// ---------------------------------------------------------------------------
__global__ __launch_bounds__(256) void vq_out(
        const float* __restrict__ z, const float* __restrict__ w,
        const unsigned long long* __restrict__ keys,
        float* __restrict__ out, float* __restrict__ partial) {
    __shared__ float red[4];
    const int tid = threadIdx.x;
    const int base = (blockIdx.x * 256 + tid) * 4;   // multiple of 4; s+3 < 4096
    const int n = base >> 20;
    const int r = base & (NSTRIDE - 1);
    const int d = r >> 12;
    const int s = r & (SPATIAL - 1);
    const int p0 = (n << 12) | s;

    const int e0 = (int)(keys[p0 + 0] & 8191ull);
    const int e1 = (int)(keys[p0 + 1] & 8191ull);
    const int e2 = (int)(keys[p0 + 2] & 8191ull);
    const int e3 = (int)(keys[p0 + 3] & 8191ull);

    const float4 zl = *(const float4*)(z + base);
    const float zq0 = w[(size_t)e0 * DIM + d];
    const float zq1 = w[(size_t)e1 * DIM + d];
    const float zq2 = w[(size_t)e2 * DIM + d];
    const float zq3 = w[(size_t)e3 * DIM + d];

    float4 o;
    o.x = zl.x + (zq0 - zl.x);
    o.y = zl.y + (zq1 - zl.y);
    o.z = zl.z + (zq2 - zl.z);
    o.w = zl.w + (zq3 - zl.w);
    *(float4*)(out + base) = o;

    float d0 = zq0 - zl.x, d1 = zq1 - zl.y, d2 = zq2 - zl.z, d3 = zq3 - zl.w;
    float ls = d0 * d0 + d1 * d1 + d2 * d2 + d3 * d3;
    #pragma unroll
    for (int off = 32; off; off >>= 1) ls += __shfl_down(ls, off);
    if ((tid & 63) == 0) red[tid >> 6] = ls;

    if (base < NPOS) {
        const int eb0 = (int)(keys[base + 0] & 8191ull);
        const int eb1 = (int)(keys[base + 1] & 8191ull);
        const int eb2 = (int)(keys[base + 2] & 8191ull);
        const int eb3 = (int)(keys[base + 3] & 8191ull);
        float4 fi = { (float)eb0, (float)eb1, (float)eb2, (float)eb3 };
        *(float4*)(out + ZELEMS + 1 + base) = fi;
    }
    __syncthreads();
    if (tid == 0) partial[blockIdx.x] = red[0] + red[1] + red[2] + red[3];
}

__global__ void vq_loss_final(const float* __restrict__ partial, float* __restrict__ out) {
    __shared__ float red[4];
    float sum = 0.f;
    for (int i = threadIdx.x; i < NOUTBLK; i += 256) sum += partial[i];
    #pragma unroll
    for (int off = 32; off; off >>= 1) sum += __shfl_down(sum, off);
    if ((threadIdx.x & 63) == 0) red[threadIdx.x >> 6] = sum;
    __syncthreads();
    if (threadIdx.x == 0)
        out[ZELEMS] = 1.25f * (red[0] + red[1] + red[2] + red[3]) / (float)ZELEMS;
}

// ---------------------------------------------------------------------------
extern "C" void kernel_launch(void* const* d_in, const int* in_sizes, int n_in,
                              void* d_out, int out_size, void* d_ws, size_t ws_size,
                              hipStream_t stream) {
    const float* z = (const float*)d_in[0];
    const float* w = (const float*)d_in[1];
    float* out = (float*)d_out;

    char* wsb = (char*)d_ws;
    _Float16* Apk = (_Float16*)(wsb);                                  //  9,437,184
    _Float16* Bpk = (_Float16*)(wsb + 9437184);                        //  9,437,184
    unsigned long long* parts = (unsigned long long*)(wsb + 18874368); //  2,097,152
    unsigned long long* keys  = (unsigned long long*)(wsb + 20971520); //     65,536
    int*   count   = (int*)(wsb + 21037056);                           //          4
    int*   list    = (int*)(wsb + 21037072);                           //     32,768
    float* partial = (float*)(wsb + 21069856);                         //      8,192

    conv_fused<<<128 + NE / 4, 256, 0, stream>>>(z, w, Apk, Bpk, count);
    vq_gemm<<<(NPOS / PBLK) * ES, 512, 0, stream>>>(Apk, Bpk, parts);
    vq_combine<<<NPOS / 256, 256, 0, stream>>>(parts, keys, count, list);
    vq_exact<<<1024, 256, 0, stream>>>(z, w, list, count, keys);
    vq_out<<<NOUTBLK, 256, 0, stream>>>(z, w, keys, out, partial);
    vq_loss_final<<<1, 256, 0, stream>>>(partial, out);
}